// Round 4
// baseline (90.414 us; speedup 1.0000x reference)
//
#include <hip/hip_runtime.h>
#include <hip/hip_bf16.h>

typedef short short8 __attribute__((ext_vector_type(8)));
typedef short short4v __attribute__((ext_vector_type(4)));
typedef float f32x4 __attribute__((ext_vector_type(4)));

#define HID 4096
#define CST 68   // f32 LDS row stride for cayley kernel
#define TPB 8    // tokens per block in kron kernel

__device__ __forceinline__ unsigned short f2bf(float f) {
    unsigned int u = __float_as_uint(f);
    u = (u + 0x7FFFu + ((u >> 16) & 1u)) >> 16;
    return (unsigned short)u;
}

// f32x4 = row i of SA (64x64, stride CST) times SB columns j0..j0+3
__device__ __forceinline__ f32x4 mm4(const float* SA, const float* SB, int i, int j0) {
    f32x4 acc = {0.f, 0.f, 0.f, 0.f};
#pragma unroll 8
    for (int k = 0; k < 64; ++k) {
        float a = SA[i * CST + k];
        acc += a * *reinterpret_cast<const f32x4*>(SB + k * CST + j0);
    }
    return acc;
}

// ---------- Kernel 1: Cayley (Neumann product form) + M-build, fused ----------
// grid=2 (block 0: left/PL, block 1: right/MRT), 1024 threads.
// Q = I + 2*(Y + ... + Y^8), Y = X/2, X = triu(raw,1)-triu(raw,1)^T.
__global__ __launch_bounds__(1024) void cayley_build_kernel(
    const float* __restrict__ rul, const float* __restrict__ rvl, const float* __restrict__ dl,
    const float* __restrict__ rur, const float* __restrict__ rvr, const float* __restrict__ dr,
    const int* __restrict__ invt,
    unsigned short* __restrict__ plb, unsigned short* __restrict__ mrtb)
{
    __shared__ __align__(16) float Yw[64 * CST], Aw[64 * CST], Pw[64 * CST];
    __shared__ __align__(16) float Qw[64 * CST], QTw[64 * CST];
    __shared__ float dd[64];

    const float* ru; const float* rv; const float* dv; unsigned short* ob;
    if (blockIdx.x == 0) { ru = rul; rv = rvl; dv = dl; ob = plb; }
    else                 { ru = rur; rv = rvr; dv = dr; ob = mrtb; }

    const int tid = threadIdx.x;
    const int i = tid >> 4;
    const int j0 = (tid & 15) << 2;

    for (int pass = 0; pass < 2; ++pass) {
        const float* raw = (pass == 0) ? ru : rv;
#pragma unroll
        for (int q = 0; q < 4; ++q) {
            int j = j0 + q;
            float v = 0.f;
            if (j > i)      v =  raw[i * 64 + j];
            else if (j < i) v = -raw[j * 64 + i];
            Yw[i * CST + j] = 0.5f * v;
        }
        __syncthreads();
        f32x4 a = mm4(Yw, Yw, i, j0);                    // A = Y*Y
        __syncthreads();
        *reinterpret_cast<f32x4*>(Aw + i * CST + j0) = a;
        *reinterpret_cast<f32x4*>(Pw + i * CST + j0) =   // P = Y + A
            a + *reinterpret_cast<const f32x4*>(Yw + i * CST + j0);
        __syncthreads();
        a = mm4(Pw, Aw, i, j0);                          // P += P*A
        __syncthreads();
        *reinterpret_cast<f32x4*>(Pw + i * CST + j0) += a;
        __syncthreads();
        a = mm4(Aw, Aw, i, j0);                          // A = A*A
        __syncthreads();
        *reinterpret_cast<f32x4*>(Aw + i * CST + j0) = a;
        __syncthreads();
        a = mm4(Pw, Aw, i, j0);                          // P += P*A
        __syncthreads();
        f32x4 p = *reinterpret_cast<const f32x4*>(Pw + i * CST + j0) + a;
#pragma unroll
        for (int q = 0; q < 4; ++q) {
            int j = j0 + q;
            float qv = ((i == j) ? 1.f : 0.f) + 2.f * p[q];
            if (pass == 0) Qw[i * CST + j]  = qv;   // Qu[i][j]
            else           QTw[j * CST + i] = qv;   // Qv^T
        }
        __syncthreads();
    }
    if (tid < 64) { float d = dv[tid]; dd[tid] = (invt[0] != 0) ? (1.0f / d) : d; }
    __syncthreads();

    f32x4 m = {0.f, 0.f, 0.f, 0.f};
#pragma unroll 8
    for (int j = 0; j < 64; ++j) {
        float aa = Qw[i * CST + j] * dd[j];
        m += aa * *reinterpret_cast<const f32x4*>(QTw + j * CST + j0);
    }
#pragma unroll
    for (int q = 0; q < 4; ++q)
        ob[(j0 + q) * 64 + i] = f2bf(m[q]);
}

// ---------- Kernel 2: block-cooperative streaming kron ----------
// Block = 4 waves; wave w owns rows 16w..16w+15 of each token.
// Per token: matmul1 Z-rows = (Xrows .* ds) * MR  (A from regs, prefetched),
// Zt (shared LDS) transpose, raw-barrier (lgkm only, vmcnt stays in flight),
// matmul2 Y^T-rows = Z^T-rows * PL^T, dwordx4 stores.
#define PREFETCH(X, PTR) do { \
    const float* _p = (PTR); \
    X##0 = *reinterpret_cast<const f32x4*>(_p); \
    X##1 = *reinterpret_cast<const f32x4*>(_p + 4); \
    X##2 = *reinterpret_cast<const f32x4*>(_p + 32); \
    X##3 = *reinterpret_cast<const f32x4*>(_p + 36); \
} while (0)

#define TOKEN_BODY(T, X) do { \
    short8 a1[2]; \
    { \
        f32x4 v00 = X##0 * dsr[0]; \
        f32x4 v01 = X##1 * dsr[1]; \
        f32x4 v10 = X##2 * dsr[2]; \
        f32x4 v11 = X##3 * dsr[3]; \
        short8 f0, f1; \
        _Pragma("unroll") \
        for (int e = 0; e < 4; ++e) { \
            f0[e] = (short)f2bf(v00[e]); f0[e + 4] = (short)f2bf(v01[e]); \
            f1[e] = (short)f2bf(v10[e]); f1[e + 4] = (short)f2bf(v11[e]); \
        } \
        a1[0] = f0; a1[1] = f1; \
    } \
    f32x4 acc[4]; \
    { f32x4 z = {0.f,0.f,0.f,0.f}; acc[0]=z; acc[1]=z; acc[2]=z; acc[3]=z; } \
    _Pragma("unroll") \
    for (int s = 0; s < 2; ++s) { \
        _Pragma("unroll") \
        for (int tc = 0; tc < 4; ++tc) \
            acc[tc] = __builtin_amdgcn_mfma_f32_16x16x32_bf16(a1[s], bmr[s][tc], acc[tc], 0, 0, 0); \
    } \
    _Pragma("unroll") \
    for (int tc = 0; tc < 4; ++tc) { \
        short4v zz; \
        _Pragma("unroll") \
        for (int r = 0; r < 4; ++r) zz[r] = (short)f2bf(acc[tc][r]); \
        *reinterpret_cast<short4v*>(Zt + (tc * 16 + l15) * 72 + w * 16 + lg * 4) = zz; \
    } \
    asm volatile("s_waitcnt lgkmcnt(0)" ::: "memory"); \
    __builtin_amdgcn_sched_barrier(0); \
    __builtin_amdgcn_s_barrier(); \
    short8 a20 = *reinterpret_cast<const short8*>(Zt + (w * 16 + l15) * 72 + lg * 8); \
    short8 a21 = *reinterpret_cast<const short8*>(Zt + (w * 16 + l15) * 72 + 32 + lg * 8); \
    f32x4 y[4]; \
    { f32x4 z = {0.f,0.f,0.f,0.f}; y[0]=z; y[1]=z; y[2]=z; y[3]=z; } \
    _Pragma("unroll") \
    for (int tc = 0; tc < 4; ++tc) { \
        y[tc] = __builtin_amdgcn_mfma_f32_16x16x32_bf16(a20, bpl[0][tc], y[tc], 0, 0, 0); \
        y[tc] = __builtin_amdgcn_mfma_f32_16x16x32_bf16(a21, bpl[1][tc], y[tc], 0, 0, 0); \
    } \
    float* _op = out + (size_t)(T) * HID + w * 16 + lg * 4; \
    _Pragma("unroll") \
    for (int tc = 0; tc < 4; ++tc) \
        *reinterpret_cast<f32x4*>(_op + (tc * 16 + l15) * 64) = y[tc]; \
    __builtin_amdgcn_sched_barrier(0); \
    __builtin_amdgcn_s_barrier(); \
} while (0)

__global__ __launch_bounds__(256, 3) void kron_kernel(
    const float* __restrict__ inp, const float* __restrict__ ds,
    const unsigned short* __restrict__ plb, const unsigned short* __restrict__ mrtb,
    const int* __restrict__ invt, float* __restrict__ out, int ntok)
{
    __shared__ __align__(16) unsigned short Zt[64 * 72];
    const int w = threadIdx.x >> 6;
    const int lane = threadIdx.x & 63;
    const int l15 = lane & 15;
    const int lg = lane >> 4;
    // this lane's global element base within a token: row 16w+l15, col 8lg
    const int rowbase = (w * 16 + l15) * 64 + lg * 8;

    // persistent B fragments
    short8 bmr[2][4], bpl[2][4];
#pragma unroll
    for (int tc = 0; tc < 4; ++tc)
#pragma unroll
        for (int s = 0; s < 2; ++s) {
            bmr[s][tc] = *reinterpret_cast<const short8*>(
                mrtb + (tc * 16 + l15) * 64 + s * 32 + lg * 8);
            bpl[s][tc] = *reinterpret_cast<const short8*>(
                plb + (tc * 16 + l15) * 64 + s * 32 + lg * 8);
        }

    // persistent ds rows (inversion pre-applied)
    const bool inv = (invt[0] != 0);
    f32x4 dsr[4];
    dsr[0] = *reinterpret_cast<const f32x4*>(ds + rowbase);
    dsr[1] = *reinterpret_cast<const f32x4*>(ds + rowbase + 4);
    dsr[2] = *reinterpret_cast<const f32x4*>(ds + rowbase + 32);
    dsr[3] = *reinterpret_cast<const f32x4*>(ds + rowbase + 36);
    if (inv) {
#pragma unroll
        for (int q = 0; q < 4; ++q)
#pragma unroll
            for (int e = 0; e < 4; ++e) dsr[q][e] = 1.0f / dsr[q][e];
    }

    const int t0 = blockIdx.x * TPB;
    int ntl = ntok - t0;
    if (ntl <= 0) return;
    if (ntl > TPB) ntl = TPB;

    f32x4 xA0, xA1, xA2, xA3, xB0, xB1, xB2, xB3;
    PREFETCH(xA, inp + (size_t)t0 * HID + rowbase);

    for (int it = 0; it < ntl; ++it) {
        const int t = t0 + it;
        if ((it & 1) == 0) {
            if (it + 1 < ntl) PREFETCH(xB, inp + (size_t)(t + 1) * HID + rowbase);
            TOKEN_BODY(t, xA);
        } else {
            if (it + 1 < ntl) PREFETCH(xA, inp + (size_t)(t + 1) * HID + rowbase);
            TOKEN_BODY(t, xB);
        }
    }
}

extern "C" void kernel_launch(void* const* d_in, const int* in_sizes, int n_in,
                              void* d_out, int out_size, void* d_ws, size_t ws_size,
                              hipStream_t stream) {
    const float* inp = (const float*)d_in[0];
    const float* rul = (const float*)d_in[1];
    const float* rvl = (const float*)d_in[2];
    const float* dl  = (const float*)d_in[3];
    const float* rur = (const float*)d_in[4];
    const float* rvr = (const float*)d_in[5];
    const float* dr  = (const float*)d_in[6];
    const float* ds  = (const float*)d_in[7];
    const int*   invt = (const int*)d_in[8];
    float* out = (float*)d_out;

    unsigned short* plb  = (unsigned short*)d_ws;   // 4096 bf16
    unsigned short* mrtb = plb + 4096;              // 4096 bf16

    const int ntok = in_sizes[0] / HID;

    hipLaunchKernelGGL(cayley_build_kernel, dim3(2), dim3(1024), 0, stream,
                       rul, rvl, dl, rur, rvr, dr, invt, plb, mrtb);
    const int nblk = (ntok + TPB - 1) / TPB;
    hipLaunchKernelGGL(kron_kernel, dim3(nblk), dim3(256), 0, stream,
                       inp, ds, plb, mrtb, invt, out, ntok);
}

// Round 5
// 87.684 us; speedup vs baseline: 1.0311x; 1.0311x over previous
//
#include <hip/hip_runtime.h>
#include <hip/hip_bf16.h>

typedef short short8 __attribute__((ext_vector_type(8)));
typedef short short4v __attribute__((ext_vector_type(4)));
typedef float f32x4 __attribute__((ext_vector_type(4)));

#define HID 4096
#define CST 68   // f32 LDS row stride for cayley kernel
#define G    4   // tokens per pipeline group
#define NGRP 4   // groups per block -> 16 tokens per block

__device__ __forceinline__ unsigned short f2bf(float f) {
    unsigned int u = __float_as_uint(f);
    u = (u + 0x7FFFu + ((u >> 16) & 1u)) >> 16;
    return (unsigned short)u;
}

// f32x4 = row i of SA (64x64, stride CST) times SB columns j0..j0+3
__device__ __forceinline__ f32x4 mm4(const float* SA, const float* SB, int i, int j0) {
    f32x4 acc = {0.f, 0.f, 0.f, 0.f};
#pragma unroll 8
    for (int k = 0; k < 64; ++k) {
        float a = SA[i * CST + k];
        acc += a * *reinterpret_cast<const f32x4*>(SB + k * CST + j0);
    }
    return acc;
}

// ---------- Kernel 1: Cayley (Neumann product form) + M-build, fused ----------
// grid=2 (block 0: left/PL, block 1: right/MRT), 1024 threads.
// Q = I + 2*(Y + ... + Y^8), Y = X/2, X = triu(raw,1)-triu(raw,1)^T.
__global__ __launch_bounds__(1024) void cayley_build_kernel(
    const float* __restrict__ rul, const float* __restrict__ rvl, const float* __restrict__ dl,
    const float* __restrict__ rur, const float* __restrict__ rvr, const float* __restrict__ dr,
    const int* __restrict__ invt,
    unsigned short* __restrict__ plb, unsigned short* __restrict__ mrtb)
{
    __shared__ __align__(16) float Yw[64 * CST], Aw[64 * CST], Pw[64 * CST];
    __shared__ __align__(16) float Qw[64 * CST], QTw[64 * CST];
    __shared__ float dd[64];

    const float* ru; const float* rv; const float* dv; unsigned short* ob;
    if (blockIdx.x == 0) { ru = rul; rv = rvl; dv = dl; ob = plb; }
    else                 { ru = rur; rv = rvr; dv = dr; ob = mrtb; }

    const int tid = threadIdx.x;
    const int i = tid >> 4;
    const int j0 = (tid & 15) << 2;

    for (int pass = 0; pass < 2; ++pass) {
        const float* raw = (pass == 0) ? ru : rv;
#pragma unroll
        for (int q = 0; q < 4; ++q) {
            int j = j0 + q;
            float v = 0.f;
            if (j > i)      v =  raw[i * 64 + j];
            else if (j < i) v = -raw[j * 64 + i];
            Yw[i * CST + j] = 0.5f * v;
        }
        __syncthreads();
        f32x4 a = mm4(Yw, Yw, i, j0);                    // A = Y*Y
        __syncthreads();
        *reinterpret_cast<f32x4*>(Aw + i * CST + j0) = a;
        *reinterpret_cast<f32x4*>(Pw + i * CST + j0) =   // P = Y + A
            a + *reinterpret_cast<const f32x4*>(Yw + i * CST + j0);
        __syncthreads();
        a = mm4(Pw, Aw, i, j0);                          // P += P*A
        __syncthreads();
        *reinterpret_cast<f32x4*>(Pw + i * CST + j0) += a;
        __syncthreads();
        a = mm4(Aw, Aw, i, j0);                          // A = A*A
        __syncthreads();
        *reinterpret_cast<f32x4*>(Aw + i * CST + j0) = a;
        __syncthreads();
        a = mm4(Pw, Aw, i, j0);                          // P += P*A
        __syncthreads();
        f32x4 p = *reinterpret_cast<const f32x4*>(Pw + i * CST + j0) + a;
#pragma unroll
        for (int q = 0; q < 4; ++q) {
            int j = j0 + q;
            float qv = ((i == j) ? 1.f : 0.f) + 2.f * p[q];
            if (pass == 0) Qw[i * CST + j]  = qv;   // Qu[i][j]
            else           QTw[j * CST + i] = qv;   // Qv^T
        }
        __syncthreads();
    }
    if (tid < 64) { float d = dv[tid]; dd[tid] = (invt[0] != 0) ? (1.0f / d) : d; }
    __syncthreads();

    f32x4 m = {0.f, 0.f, 0.f, 0.f};
#pragma unroll 8
    for (int j = 0; j < 64; ++j) {
        float aa = Qw[i * CST + j] * dd[j];
        m += aa * *reinterpret_cast<const f32x4*>(QTw + j * CST + j0);
    }
#pragma unroll
    for (int q = 0; q < 4; ++q)
        ob[(j0 + q) * 64 + i] = f2bf(m[q]);
}

// ---------- Kernel 2: group-pipelined cooperative kron ----------
// Block = 4 waves; wave w owns rows 16w..16w+15 of each token.
// Pipeline in groups of G=4 tokens:
//   cvt(Gg) [one counted vmcnt wait per group; loads are oldest outstanding]
//   -> issue loads(G_{g+1}) into freed landing buffer
//   -> mfma1 + Zt writes x4 -> barrier -> mfma2 + stores x4 -> barrier
__global__ __launch_bounds__(256, 2) void kron_kernel(
    const float* __restrict__ inp, const float* __restrict__ ds,
    const unsigned short* __restrict__ plb, const unsigned short* __restrict__ mrtb,
    const int* __restrict__ invt, float* __restrict__ out, int ntok)
{
    __shared__ __align__(16) unsigned short Zt[G][64 * 72];
    const int w = threadIdx.x >> 6;
    const int lane = threadIdx.x & 63;
    const int l15 = lane & 15;
    const int lg = lane >> 4;
    // lane's slice of a token: row 16w+l15, cols lg*8 + {0..7, 32..39}
    const int rowbase = (w * 16 + l15) * 64 + lg * 8;

    // persistent B fragments
    short8 bmr[2][4], bpl[2][4];
#pragma unroll
    for (int tc = 0; tc < 4; ++tc)
#pragma unroll
        for (int s = 0; s < 2; ++s) {
            bmr[s][tc] = *reinterpret_cast<const short8*>(
                mrtb + (tc * 16 + l15) * 64 + s * 32 + lg * 8);
            bpl[s][tc] = *reinterpret_cast<const short8*>(
                plb + (tc * 16 + l15) * 64 + s * 32 + lg * 8);
        }

    // persistent ds rows (inversion pre-applied)
    const bool inv = (invt[0] != 0);
    f32x4 dsr[4];
    dsr[0] = *reinterpret_cast<const f32x4*>(ds + rowbase);
    dsr[1] = *reinterpret_cast<const f32x4*>(ds + rowbase + 4);
    dsr[2] = *reinterpret_cast<const f32x4*>(ds + rowbase + 32);
    dsr[3] = *reinterpret_cast<const f32x4*>(ds + rowbase + 36);
    if (inv) {
#pragma unroll
        for (int q = 0; q < 4; ++q)
#pragma unroll
            for (int e = 0; e < 4; ++e) dsr[q][e] = 1.0f / dsr[q][e];
    }

    const int t00 = blockIdx.x * (G * NGRP);
    if (t00 >= ntok) return;

    f32x4 xb[G][4];   // landing buffer, fully unrolled indexing only

    // prologue: load group 0
    {
        const float* p = inp + (size_t)t00 * HID + rowbase;
#pragma unroll
        for (int u = 0; u < G; ++u) {
            if (t00 + u < ntok) {
                const float* q = p + u * HID;
                xb[u][0] = *reinterpret_cast<const f32x4*>(q);
                xb[u][1] = *reinterpret_cast<const f32x4*>(q + 4);
                xb[u][2] = *reinterpret_cast<const f32x4*>(q + 32);
                xb[u][3] = *reinterpret_cast<const f32x4*>(q + 36);
            }
        }
    }

    for (int gg = 0; gg < NGRP; ++gg) {
        const int tb = t00 + gg * G;

        // ---- cvt phase: consume landing buffer -> bf16 A-frags ----
        short8 a1[G][2];
#pragma unroll
        for (int u = 0; u < G; ++u) {
            f32x4 v0 = xb[u][0] * dsr[0];
            f32x4 v1 = xb[u][1] * dsr[1];
            f32x4 v2 = xb[u][2] * dsr[2];
            f32x4 v3 = xb[u][3] * dsr[3];
            short8 f0, f1;
#pragma unroll
            for (int e = 0; e < 4; ++e) {
                f0[e] = (short)f2bf(v0[e]); f0[e + 4] = (short)f2bf(v1[e]);
                f1[e] = (short)f2bf(v2[e]); f1[e + 4] = (short)f2bf(v3[e]);
            }
            a1[u][0] = f0; a1[u][1] = f1;
        }

        // ---- issue next group's loads into the freed landing buffer ----
        if (gg + 1 < NGRP) {
            const int tn = tb + G;
            const float* p = inp + (size_t)tn * HID + rowbase;
#pragma unroll
            for (int u = 0; u < G; ++u) {
                if (tn + u < ntok) {
                    const float* q = p + u * HID;
                    xb[u][0] = *reinterpret_cast<const f32x4*>(q);
                    xb[u][1] = *reinterpret_cast<const f32x4*>(q + 4);
                    xb[u][2] = *reinterpret_cast<const f32x4*>(q + 32);
                    xb[u][3] = *reinterpret_cast<const f32x4*>(q + 36);
                }
            }
        }

        // ---- phase 1: Z = (X.*ds)*MR, transpose into Zt ----
#pragma unroll
        for (int u = 0; u < G; ++u) {
            f32x4 acc[4];
            { f32x4 z = {0.f,0.f,0.f,0.f}; acc[0]=z; acc[1]=z; acc[2]=z; acc[3]=z; }
#pragma unroll
            for (int s = 0; s < 2; ++s)
#pragma unroll
                for (int tc = 0; tc < 4; ++tc)
                    acc[tc] = __builtin_amdgcn_mfma_f32_16x16x32_bf16(a1[u][s], bmr[s][tc], acc[tc], 0, 0, 0);
#pragma unroll
            for (int tc = 0; tc < 4; ++tc) {
                short4v zz;
#pragma unroll
                for (int r = 0; r < 4; ++r) zz[r] = (short)f2bf(acc[tc][r]);
                *reinterpret_cast<short4v*>(&Zt[u][(tc * 16 + l15) * 72 + w * 16 + lg * 4]) = zz;
            }
        }
        asm volatile("s_waitcnt lgkmcnt(0)" ::: "memory");
        __builtin_amdgcn_sched_barrier(0);
        __builtin_amdgcn_s_barrier();

        // ---- phase 2: Out^T = Z^T * PL^T, f32x4 stores ----
#pragma unroll
        for (int u = 0; u < G; ++u) {
            short8 a20 = *reinterpret_cast<const short8*>(&Zt[u][(w * 16 + l15) * 72 + lg * 8]);
            short8 a21 = *reinterpret_cast<const short8*>(&Zt[u][(w * 16 + l15) * 72 + 32 + lg * 8]);
            f32x4 y[4];
            { f32x4 z = {0.f,0.f,0.f,0.f}; y[0]=z; y[1]=z; y[2]=z; y[3]=z; }
#pragma unroll
            for (int tc = 0; tc < 4; ++tc) {
                y[tc] = __builtin_amdgcn_mfma_f32_16x16x32_bf16(a20, bpl[0][tc], y[tc], 0, 0, 0);
                y[tc] = __builtin_amdgcn_mfma_f32_16x16x32_bf16(a21, bpl[1][tc], y[tc], 0, 0, 0);
            }
            if (tb + u < ntok) {
                float* op = out + (size_t)(tb + u) * HID + w * 16 + lg * 4;
#pragma unroll
                for (int tc = 0; tc < 4; ++tc)
                    *reinterpret_cast<f32x4*>(op + (tc * 16 + l15) * 64) = y[tc];
            }
        }
        __builtin_amdgcn_sched_barrier(0);
        __builtin_amdgcn_s_barrier();
    }
}

extern "C" void kernel_launch(void* const* d_in, const int* in_sizes, int n_in,
                              void* d_out, int out_size, void* d_ws, size_t ws_size,
                              hipStream_t stream) {
    const float* inp = (const float*)d_in[0];
    const float* rul = (const float*)d_in[1];
    const float* rvl = (const float*)d_in[2];
    const float* dl  = (const float*)d_in[3];
    const float* rur = (const float*)d_in[4];
    const float* rvr = (const float*)d_in[5];
    const float* dr  = (const float*)d_in[6];
    const float* ds  = (const float*)d_in[7];
    const int*   invt = (const int*)d_in[8];
    float* out = (float*)d_out;

    unsigned short* plb  = (unsigned short*)d_ws;   // 4096 bf16
    unsigned short* mrtb = plb + 4096;              // 4096 bf16

    const int ntok = in_sizes[0] / HID;

    hipLaunchKernelGGL(cayley_build_kernel, dim3(2), dim3(1024), 0, stream,
                       rul, rvl, dl, rur, rvr, dr, invt, plb, mrtb);
    const int tpb = G * NGRP;
    const int nblk = (ntok + tpb - 1) / tpb;
    hipLaunchKernelGGL(kron_kernel, dim3(nblk), dim3(256), 0, stream,
                       inp, ds, plb, mrtb, invt, out, ntok);
}